// Round 6
// baseline (1338.164 us; speedup 1.0000x reference)
//
#include <hip/hip_runtime.h>
#include <hip/hip_cooperative_groups.h>
#include <stdint.h>
#include <stddef.h>

namespace cg = cooperative_groups;

// z = x[32768,512] @ W[2048,512]^T + B; per-row instance-norm over 2048;
// out = (z_norm + y) * y.  f32 I/O, bf16 MFMA (32x32x16) internally.
//
// Persistent cooperative: 256 blocks (1/CU), 8 waves, 4 generations of BM=32.
// grid.sync() at each phase boundary keeps ALL blocks' K-phases (L2-bound,
// Wb-hot) time-separated from epilogue phases (HBM streaming) — rounds 2-5
// showed phase mixing evicts the 2MB L2-resident Wb and collapses to
// latency-bound 16B loads (2 TB/s, 4x traffic amplification).

typedef float  f32x16_t __attribute__((ext_vector_type(16)));
typedef float  f32x4    __attribute__((ext_vector_type(4)));
typedef short  short8_t __attribute__((ext_vector_type(8)));

#define BATCH   32768
#define INF     512
#define OUTF    2048
#define BM      32
#define GENS    4
#define ROWS_PER_BLK (BM * GENS)         // 128
#define NBLK    (BATCH / ROWS_PER_BLK)   // 256
#define THREADS 512
#define WB_BYTES (OUTF * INF * 2)        // 2 MB bf16 W

// LDS layout
#define A_OFF(p)   ((p) * 32768)         // 2 x 32 KB A tiles (bf16)
#define ST_OFF(p)  (65536 + (p) * 2048)  // 2 x [8 waves][32 rows][2] f32
#define RS_OFF(p)  (69632 + (p) * 256)   // 2 x [32][2] f32 (mean, rstd)
#define SMEM_BYTES 70144

__device__ __forceinline__ unsigned short f2bf(float f) {
    unsigned int u = __builtin_bit_cast(unsigned int, f);
    u += 0x7FFFu + ((u >> 16) & 1u);     // round-to-nearest-even
    return (unsigned short)(u >> 16);
}

__device__ __forceinline__ short8_t pack8(f32x4 a, f32x4 b) {
    short8_t v;
    v[0] = (short)f2bf(a[0]); v[1] = (short)f2bf(a[1]);
    v[2] = (short)f2bf(a[2]); v[3] = (short)f2bf(a[3]);
    v[4] = (short)f2bf(b[0]); v[5] = (short)f2bf(b[1]);
    v[6] = (short)f2bf(b[2]); v[7] = (short)f2bf(b[3]);
    return v;
}

__device__ __forceinline__ f32x4 ld4(const float* p) {
    return *(const f32x4*)p;
}

// Prepass: W f32 [2048,512] -> Wb bf16, frag-major for 32x32x16:
// elem(s, col, half, j) at s*32768 + col*16 + half*8 + j   (k = s*16 + half*8 + j)
__global__ __launch_bounds__(256) void conv_w_kernel(const float* __restrict__ W,
                                                     unsigned short* __restrict__ Wb) {
    int id  = blockIdx.x * 256 + threadIdx.x;   // col*64 + k8
    int col = id >> 6;
    int k8  = id & 63;
    const float* src = W + (size_t)col * INF + k8 * 8;
    f32x4 a = *(const f32x4*)src;
    f32x4 b = *(const f32x4*)(src + 4);
    *(short8_t*)(Wb + (size_t)(k8 >> 1) * 32768 + col * 16 + (k8 & 1) * 8) = pack8(a, b);
}

// A-frag (32x32x16): lane l -> A[row = l&31][k = s*16 + (l>>5)*8 + j], j=0..7
// A LDS addr(s,row,half) = s*1024 + row*32 + half*16  (bytes)
// C-frag: col = lane&31, row = (q&3) + 8*(q>>2) + 4*(lane>>5), q=0..15
template <bool USE_WB>
__global__ __launch_bounds__(THREADS, 2) void fused_kernel(
    const float* __restrict__ x, const float* __restrict__ y,
    const float* __restrict__ W, const float* __restrict__ Bias,
    const unsigned short* __restrict__ Wb, float* __restrict__ out) {

    __shared__ __align__(16) char smem[SMEM_BYTES];
    cg::grid_group grid = cg::this_grid();

    const int t    = threadIdx.x;
    const int w    = t >> 6;
    const int l    = t & 63;
    const int c31  = l & 31;
    const int half = l >> 5;
    const int m_base = blockIdx.x * ROWS_PER_BLK;

    // bias per lane: one value per 32-col frag
    float biasv[8];
    #pragma unroll
    for (int ni = 0; ni < 8; ++ni)
        biasv[ni] = Bias[w * 256 + ni * 32 + c31];

    // W access bases
    const char* wbase = nullptr;     // + s*65536 + ni*1024 (bytes)
    const float* wf   = nullptr;     // + ni*32*INF + s*16  (elems)
    if (USE_WB) wbase = (const char*)Wb + (size_t)(w * 256 + c31) * 32 + half * 16;
    else        wf    = W + (size_t)(w * 256 + c31) * INF + half * 8;

    // ---- prologue: stage gen 0 into A[0] (wave w -> rows w, w+8, w+16, w+24) ----
    {
        char* Ab = smem + A_OFF(0);
        const float* xs = x + (size_t)(m_base + w) * INF + l * 8;
        char* dst = Ab + (l >> 1) * 1024 + w * 32 + (l & 1) * 16;
        #pragma unroll
        for (int i = 0; i < 4; ++i) {   // row = w + 8i, k8 = l
            f32x4 a = ld4(xs + i * 8 * INF);
            f32x4 b = ld4(xs + i * 8 * INF + 4);
            *(short8_t*)(dst + i * 256) = pack8(a, b);
        }
    }
    __syncthreads();

    for (int g = 0; g < GENS; ++g) {
        const int par = g & 1;
        const char* Acur    = smem + A_OFF(par);
        char*       Anxt    = smem + A_OFF(par ^ 1);
        float*      stats   = (float*)(smem + ST_OFF(par));
        float*      rowstat = (float*)(smem + RS_OFF(par));
        const bool  stage_next = (g + 1 < GENS);

        f32x16_t acc[8];
        #pragma unroll
        for (int ni = 0; ni < 8; ++ni)
            acc[ni] = (f32x16_t)(0.0f);

        // early-issue next-gen x loads (land during this K-loop)
        f32x4 xa0, xb0, xa1, xb1, xa2, xb2, xa3, xb3;
        const float* xs = x + (size_t)(m_base + (g + 1) * BM + w) * INF + l * 8;
        if (stage_next) {
            xa0 = ld4(xs);            xb0 = ld4(xs + 4);
            xa1 = ld4(xs + 8 * INF);  xb1 = ld4(xs + 8 * INF + 4);
            xa2 = ld4(xs + 16 * INF); xb2 = ld4(xs + 16 * INF + 4);
            xa3 = ld4(xs + 24 * INF); xb3 = ld4(xs + 24 * INF + 4);
        }
        char* wdst = Anxt + (l >> 1) * 1024 + w * 32 + (l & 1) * 16;   // + i*256

        const char* aptr = Acur + c31 * 32 + half * 16;                // + s*1024

        // ---- K loop: 32 steps of K=16; W streamed from L2; one staging
        //      ds_write per 8 steps ----
        #pragma unroll
        for (int sc = 0; sc < 4; ++sc) {
            #pragma unroll
            for (int si = 0; si < 8; ++si) {
                const int s = sc * 8 + si;
                short8_t afrag = *(const short8_t*)(aptr + s * 1024);
                #pragma unroll
                for (int ni = 0; ni < 8; ++ni) {
                    short8_t bfr;
                    if (USE_WB) {
                        bfr = *(const short8_t*)(wbase + (size_t)s * 65536 + ni * 1024);
                    } else {
                        const float* p = wf + (size_t)ni * 32 * INF + s * 16;
                        bfr = pack8(*(const f32x4*)p, *(const f32x4*)(p + 4));
                    }
                    acc[ni] = __builtin_amdgcn_mfma_f32_32x32x16_bf16(afrag, bfr, acc[ni], 0, 0, 0);
                }
            }
            if (stage_next) {
                if (sc == 0) *(short8_t*)(wdst)       = pack8(xa0, xb0);
                if (sc == 1) *(short8_t*)(wdst + 256) = pack8(xa1, xb1);
                if (sc == 2) *(short8_t*)(wdst + 512) = pack8(xa2, xb2);
                if (sc == 3) *(short8_t*)(wdst + 768) = pack8(xa3, xb3);
            }
        }

        // ---- bias ----
        #pragma unroll
        for (int ni = 0; ni < 8; ++ni)
            #pragma unroll
            for (int q = 0; q < 16; ++q)
                acc[ni][q] += biasv[ni];

        // ---- per-row stats: lane partial over 8 frags, 32-lane xor reduce ----
        #pragma unroll
        for (int q = 0; q < 16; ++q) {
            float s1 = 0.f, s2 = 0.f;
            #pragma unroll
            for (int ni = 0; ni < 8; ++ni) {
                float v = acc[ni][q];
                s1 += v; s2 += v * v;
            }
            #pragma unroll
            for (int d = 1; d < 32; d <<= 1) {
                s1 += __shfl_xor(s1, d);
                s2 += __shfl_xor(s2, d);
            }
            if (c31 == 0) {
                int r = 4 * half + (q & 3) + 8 * (q >> 2);
                stats[(w * 32 + r) * 2]     = s1;
                stats[(w * 32 + r) * 2 + 1] = s2;
            }
        }
        __syncthreads();                 // stats in; A(g+1) fully staged

        if (t < 32) {
            float s1 = 0.f, s2 = 0.f;
            #pragma unroll
            for (int wi = 0; wi < 8; ++wi) {
                s1 += stats[(wi * 32 + t) * 2];
                s2 += stats[(wi * 32 + t) * 2 + 1];
            }
            float mean = s1 * (1.0f / OUTF);
            float var  = s2 * (1.0f / OUTF) - mean * mean;
            rowstat[t * 2]     = mean;
            rowstat[t * 2 + 1] = rsqrtf(var + 1e-5f);
        }
        __syncthreads();                 // rowstat ready

        // ---- phase boundary: ALL blocks finish K before ANY streams ----
        grid.sync();

        // ---- epilogue: direct frag stores; every instr = 2 full 128B lines ----
        const int m0 = m_base + g * BM;
        const int rbase = 4 * half;
        #pragma unroll
        for (int q = 0; q < 16; ++q) {
            const int r = rbase + (q & 3) + 8 * (q >> 2);
            const float mean = rowstat[r * 2];
            const float rstd = rowstat[r * 2 + 1];
            const size_t off0 = (size_t)(m0 + r) * OUTF + w * 256 + c31;
            #pragma unroll
            for (int ni = 0; ni < 8; ++ni) {
                size_t off = off0 + ni * 32;
                float yv = y[off];
                float zn = (acc[ni][q] - mean) * rstd;
                out[off] = (zn + yv) * yv;
            }
        }

        // ---- phase boundary: streaming drained before next K-phase ----
        if (g + 1 < GENS) grid.sync();
    }
}

extern "C" void kernel_launch(void* const* d_in, const int* in_sizes, int n_in,
                              void* d_out, int out_size, void* d_ws, size_t ws_size,
                              hipStream_t stream) {
    const float* x = (const float*)d_in[0];
    const float* y = (const float*)d_in[1];
    const float* W = (const float*)d_in[2];
    const float* B = (const float*)d_in[3];
    float* out = (float*)d_out;

    if (ws_size >= (size_t)WB_BYTES) {
        unsigned short* Wb = (unsigned short*)d_ws;
        conv_w_kernel<<<512, 256, 0, stream>>>(W, Wb);
        void* args[] = {(void*)&x, (void*)&y, (void*)&W, (void*)&B, (void*)&Wb, (void*)&out};
        hipLaunchCooperativeKernel((void*)fused_kernel<true>, dim3(NBLK), dim3(THREADS),
                                   args, 0, stream);
    } else {
        const unsigned short* Wb = nullptr;
        void* args[] = {(void*)&x, (void*)&y, (void*)&W, (void*)&B, (void*)&Wb, (void*)&out};
        hipLaunchCooperativeKernel((void*)fused_kernel<false>, dim3(NBLK), dim3(THREADS),
                                   args, 0, stream);
    }
}

// Round 7
// 1135.347 us; speedup vs baseline: 1.1786x; 1.1786x over previous
//
#include <hip/hip_runtime.h>
#include <stdint.h>
#include <stddef.h>

// z = x[32768,512] @ W[2048,512]^T + B; per-row instance-norm over 2048;
// out = (z_norm + y) * y.  f32 I/O, bf16 MFMA (16x16x32) internally.
//
// Round-7: non-persistent 512 blocks x 2 generations of BM=32 rows.
// Epilogue = wave-private LDS transpose (NO block barrier) + full-row 1KB
// float4 y/out bursts (the round-1 pattern that kept HBM traffic clean);
// epilogue(g) overlaps K(g+1) via wave drift. A double-buffered, staged
// during K(0) with early-issued x loads. Stats parity-buffered.

typedef float  f32x4    __attribute__((ext_vector_type(4)));
typedef float  f32x4_t  __attribute__((ext_vector_type(4)));
typedef short  short8_t __attribute__((ext_vector_type(8)));

#define BATCH   32768
#define INF     512
#define OUTF    2048
#define BM      32
#define GENS    2
#define ROWS_PER_BLK (BM * GENS)         // 64
#define NBLK    (BATCH / ROWS_PER_BLK)   // 512
#define THREADS 512
#define WB_BYTES (OUTF * INF * 2)        // 2 MB bf16 W

// LDS layout (bytes)
#define A_OFF(p)   ((p) * 32768)          // 2 x 32KB A (bf16, addr = k8*512 + row*16)
#define ST_OFF(p)  (65536 + (p) * 2048)   // 2 x [8 waves][32 rows][2] f32
#define RS_OFF(p)  (69632 + (p) * 256)    // 2 x [32][2] f32 (mean, rstd)
#define WV_OFF(w)  (70144 + (w) * 8320)   // per-wave [8 rows][260] f32 transpose buf
#define SMEM_BYTES (70144 + 8 * 8320)     // 136704

__device__ __forceinline__ unsigned short f2bf(float f) {
    unsigned int u = __builtin_bit_cast(unsigned int, f);
    u += 0x7FFFu + ((u >> 16) & 1u);     // round-to-nearest-even
    return (unsigned short)(u >> 16);
}

__device__ __forceinline__ short8_t pack8(f32x4 a, f32x4 b) {
    short8_t v;
    v[0] = (short)f2bf(a[0]); v[1] = (short)f2bf(a[1]);
    v[2] = (short)f2bf(a[2]); v[3] = (short)f2bf(a[3]);
    v[4] = (short)f2bf(b[0]); v[5] = (short)f2bf(b[1]);
    v[6] = (short)f2bf(b[2]); v[7] = (short)f2bf(b[3]);
    return v;
}

__device__ __forceinline__ f32x4 ld4(const float* p) { return *(const f32x4*)p; }

// Prepass: W f32 [2048,512] -> Wb bf16 frag-major (16x16x32):
// Wb[k8][o][j] = W[o][k8*8+j], plane size 2048*8 elems.
__global__ __launch_bounds__(256) void conv_w_kernel(const float* __restrict__ W,
                                                     unsigned short* __restrict__ Wb) {
    int id  = blockIdx.x * 256 + threadIdx.x;   // o*64 + k8
    int o   = id >> 6;
    int k8  = id & 63;
    const float* src = W + (size_t)o * INF + k8 * 8;
    f32x4 a = *(const f32x4*)src;
    f32x4 b = *(const f32x4*)(src + 4);
    *(short8_t*)(Wb + (size_t)k8 * (OUTF * 8) + o * 8) = pack8(a, b);
}

// acc[mi][ni] 16x16 C-frag: z[m0 + mi*16 + lg*4 + q][w*256 + ni*16 + l15]
template <bool USE_WB>
__global__ __launch_bounds__(THREADS, 2) void fused_kernel(
    const float* __restrict__ x, const float* __restrict__ y,
    const float* __restrict__ W, const float* __restrict__ Bias,
    const unsigned short* __restrict__ Wb, float* __restrict__ out) {

    __shared__ __align__(16) char smem[SMEM_BYTES];

    const int t   = threadIdx.x;
    const int w   = t >> 6;
    const int l   = t & 63;
    const int l15 = l & 15;
    const int lg  = l >> 4;
    const int m_base = blockIdx.x * ROWS_PER_BLK;

    float biasv[16];
    #pragma unroll
    for (int ni = 0; ni < 16; ++ni)
        biasv[ni] = Bias[w * 256 + ni * 16 + l15];

    const unsigned short* wptr = nullptr;
    const float* wf = nullptr;
    if (USE_WB) wptr = Wb + ((size_t)lg << 14) + (size_t)(w * 256 + l15) * 8; // + s*65536 + ni*128
    else        wf   = W + (size_t)(w * 256 + l15) * INF + lg * 8;            // + ni*16*INF + s*32

    // ---- prologue: stage gen 0 into A[0] (coalesced, one wave per row-pair) ----
    #pragma unroll
    for (int i = 0; i < 4; ++i) {
        int id  = i * THREADS + t;
        int row = id >> 6;          // 0..31
        int k8  = id & 63;          // 0..63
        const float* src = x + (size_t)(m_base + row) * INF + k8 * 8;
        f32x4 a = ld4(src);
        f32x4 b = ld4(src + 4);
        *(short8_t*)(smem + A_OFF(0) + k8 * 512 + row * 16) = pack8(a, b);
    }
    __syncthreads();

    for (int g = 0; g < GENS; ++g) {
        const int par = g & 1;
        const char* Acur    = smem + A_OFF(par);
        char*       Anxt    = smem + A_OFF(par ^ 1);
        float*      stats   = (float*)(smem + ST_OFF(par));
        float*      rowstat = (float*)(smem + RS_OFF(par));
        const bool  stage_next = (g + 1 < GENS);

        f32x4_t acc[2][16];
        #pragma unroll
        for (int mi = 0; mi < 2; ++mi)
            #pragma unroll
            for (int ni = 0; ni < 16; ++ni)
                acc[mi][ni] = (f32x4_t)(0.0f);

        // early-issue next-gen x loads (land during this K-loop)
        f32x4 xa0, xb0, xa1, xb1, xa2, xb2, xa3, xb3;
        const float* xs = x + (size_t)(m_base + (g + 1) * BM + w) * INF + l * 8;
        if (stage_next) {
            xa0 = ld4(xs);            xb0 = ld4(xs + 4);
            xa1 = ld4(xs + 8 * INF);  xb1 = ld4(xs + 8 * INF + 4);
            xa2 = ld4(xs + 16 * INF); xb2 = ld4(xs + 16 * INF + 4);
            xa3 = ld4(xs + 24 * INF); xb3 = ld4(xs + 24 * INF + 4);
        }
        char* wdst = Anxt + l * 512 + w * 16;   // row = w + 8i at +i*128

        const char* aptr = Acur + lg * 512 + l15 * 16;   // + s*2048 (+256 for mi=1)

        // ---- K loop: 16 steps of K=32; W streamed from L2; one staging
        //      ds_write per 4 steps ----
        #pragma unroll
        for (int sc = 0; sc < 4; ++sc) {
            #pragma unroll
            for (int si = 0; si < 4; ++si) {
                const int s = sc * 4 + si;
                short8_t a0 = *(const short8_t*)(aptr + s * 2048);
                short8_t a1 = *(const short8_t*)(aptr + s * 2048 + 256);
                #pragma unroll
                for (int ni = 0; ni < 16; ++ni) {
                    short8_t bfr;
                    if (USE_WB) {
                        bfr = *(const short8_t*)(wptr + (size_t)s * 65536 + ni * 128);
                    } else {
                        const float* p = wf + (size_t)ni * 16 * INF + s * 32;
                        bfr = pack8(*(const f32x4*)p, *(const f32x4*)(p + 4));
                    }
                    acc[0][ni] = __builtin_amdgcn_mfma_f32_16x16x32_bf16(a0, bfr, acc[0][ni], 0, 0, 0);
                    acc[1][ni] = __builtin_amdgcn_mfma_f32_16x16x32_bf16(a1, bfr, acc[1][ni], 0, 0, 0);
                }
            }
            if (stage_next) {
                if (sc == 0) *(short8_t*)(wdst)       = pack8(xa0, xb0);
                if (sc == 1) *(short8_t*)(wdst + 128) = pack8(xa1, xb1);
                if (sc == 2) *(short8_t*)(wdst + 256) = pack8(xa2, xb2);
                if (sc == 3) *(short8_t*)(wdst + 384) = pack8(xa3, xb3);
            }
        }

        // ---- bias ----
        #pragma unroll
        for (int mi = 0; mi < 2; ++mi)
            #pragma unroll
            for (int ni = 0; ni < 16; ++ni)
                #pragma unroll
                for (int q = 0; q < 4; ++q)
                    acc[mi][ni][q] += biasv[ni];

        // ---- per-row partial stats + 16-lane xor reduce ----
        #pragma unroll
        for (int mi = 0; mi < 2; ++mi) {
            #pragma unroll
            for (int q = 0; q < 4; ++q) {
                float s1 = 0.f, s2 = 0.f;
                #pragma unroll
                for (int ni = 0; ni < 16; ++ni) {
                    float v = acc[mi][ni][q];
                    s1 += v; s2 += v * v;
                }
                #pragma unroll
                for (int d = 1; d < 16; d <<= 1) {
                    s1 += __shfl_xor(s1, d);
                    s2 += __shfl_xor(s2, d);
                }
                if (l15 == 0) {
                    int r = mi * 16 + lg * 4 + q;
                    stats[(w * 32 + r) * 2]     = s1;
                    stats[(w * 32 + r) * 2 + 1] = s2;
                }
            }
        }
        __syncthreads();                 // stats in; A(g+1) fully staged

        if (t < 32) {
            float s1 = 0.f, s2 = 0.f;
            #pragma unroll
            for (int wi = 0; wi < 8; ++wi) {
                s1 += stats[(wi * 32 + t) * 2];
                s2 += stats[(wi * 32 + t) * 2 + 1];
            }
            float mean = s1 * (1.0f / OUTF);
            float var  = s2 * (1.0f / OUTF) - mean * mean;
            rowstat[t * 2]     = mean;
            rowstat[t * 2 + 1] = rsqrtf(var + 1e-5f);
        }
        __syncthreads();                 // rowstat ready; LAST barrier of gen g

        // ---- epilogue: WAVE-PRIVATE transpose, no block barrier.
        //      4 chunks of 8 rows; y/out as full-row 1KB float4 bursts. ----
        float* wbuf = (float*)(smem + WV_OFF(w));
        const int m0 = m_base + g * BM;
        #pragma unroll
        for (int c = 0; c < 4; ++c) {
            const int mi = c >> 1;
            // write this chunk's fragments (lanes whose rows fall in chunk c)
            if ((lg >> 1) == (c & 1)) {
                #pragma unroll
                for (int q = 0; q < 4; ++q)
                    #pragma unroll
                    for (int ni = 0; ni < 16; ++ni)
                        wbuf[((lg & 1) * 4 + q) * 260 + ni * 16 + l15] = acc[mi][ni][q];
            }
            __asm__ volatile("s_waitcnt lgkmcnt(0)" ::: "memory");  // wave's writes done
            #pragma unroll
            for (int i = 0; i < 8; ++i) {
                const int r = c * 8 + i;
                f32x4 z4 = *(const f32x4*)(wbuf + i * 260 + l * 4);
                const float mean = rowstat[r * 2];
                const float rstd = rowstat[r * 2 + 1];
                const size_t grow = (size_t)(m0 + r) * OUTF + w * 256 + l * 4;
                f32x4 yv = ld4(y + grow);
                f32x4 o4;
                #pragma unroll
                for (int j = 0; j < 4; ++j) {
                    float zn = (z4[j] - mean) * rstd;
                    o4[j] = (zn + yv[j]) * yv[j];
                }
                *(f32x4*)(out + grow) = o4;
            }
            __asm__ volatile("s_waitcnt lgkmcnt(0)" ::: "memory");  // reads done before reuse
        }
        // no trailing barrier: fast waves flow into K(g+1)
    }
}

extern "C" void kernel_launch(void* const* d_in, const int* in_sizes, int n_in,
                              void* d_out, int out_size, void* d_ws, size_t ws_size,
                              hipStream_t stream) {
    const float* x = (const float*)d_in[0];
    const float* y = (const float*)d_in[1];
    const float* W = (const float*)d_in[2];
    const float* B = (const float*)d_in[3];
    float* out = (float*)d_out;

    if (ws_size >= (size_t)WB_BYTES) {
        unsigned short* Wb = (unsigned short*)d_ws;
        conv_w_kernel<<<512, 256, 0, stream>>>(W, Wb);
        fused_kernel<true><<<NBLK, THREADS, 0, stream>>>(x, y, W, B, Wb, out);
    } else {
        fused_kernel<false><<<NBLK, THREADS, 0, stream>>>(x, y, W, B, nullptr, out);
    }
}

// Round 8
// 359.590 us; speedup vs baseline: 3.7214x; 3.1573x over previous
//
#include <hip/hip_runtime.h>
#include <stdint.h>
#include <stddef.h>

// z = x[32768,512] @ W[2048,512]^T + B; per-row instance-norm over 2048;
// out = (z_norm + y) * y.  f32 I/O, bf16 MFMA (16x16x32) internally.
//
// Round-8: EXACT r1 block structure (the only traffic-clean config) with
// BM=32 -> 16 so acc halves to 64 regs -> <=128 unified regs/wave ->
// 2 blocks/CU. Cross-block overlap of the HBM epilogue and L2 K-loop now
// comes from the hardware scheduler instead of in-kernel pipelining
// (which was traffic-dirty in r2-r7 for reasons never fully isolated).
// 2048 independent blocks, one 16x2048 tile each. No persistence, no gens,
// no early-issued cross-phase registers.

typedef float  f32x4    __attribute__((ext_vector_type(4)));
typedef float  f32x4_t  __attribute__((ext_vector_type(4)));
typedef short  short8_t __attribute__((ext_vector_type(8)));

#define BATCH   32768
#define INF     512
#define OUTF    2048
#define BM      16
#define NBLK    (BATCH / BM)             // 2048
#define THREADS 512
#define WB_BYTES (OUTF * INF * 2)        // 2 MB bf16 W

// LDS layout (bytes), total 50368 -> 3 blocks/CU by LDS, 2 by regs
#define A_OFF   0                        // 16 KB: [k8(64)][col(16)][16B], col = row ^ (k8&15)
#define ST_OFF  16384                    // [8 waves][16 rows][2] f32 = 1 KB
#define RS_OFF  17408                    // [16][2] f32 (mean, rstd) = 128 B
#define TB_OFF  17536                    // [4][2052] f32 transpose buf = 32832 B
#define SMEM_BYTES 50368

__device__ __forceinline__ unsigned short f2bf(float f) {
    unsigned int u = __builtin_bit_cast(unsigned int, f);
    u += 0x7FFFu + ((u >> 16) & 1u);     // round-to-nearest-even
    return (unsigned short)(u >> 16);
}

__device__ __forceinline__ short8_t pack8(f32x4 a, f32x4 b) {
    short8_t v;
    v[0] = (short)f2bf(a[0]); v[1] = (short)f2bf(a[1]);
    v[2] = (short)f2bf(a[2]); v[3] = (short)f2bf(a[3]);
    v[4] = (short)f2bf(b[0]); v[5] = (short)f2bf(b[1]);
    v[6] = (short)f2bf(b[2]); v[7] = (short)f2bf(b[3]);
    return v;
}

__device__ __forceinline__ f32x4 ld4(const float* p) { return *(const f32x4*)p; }

// Prepass: W f32 [2048,512] -> Wb bf16 frag-major (16x16x32):
// Wb[k8][o][j] = W[o][k8*8+j], plane size 2048*8 elems.
__global__ __launch_bounds__(256) void conv_w_kernel(const float* __restrict__ W,
                                                     unsigned short* __restrict__ Wb) {
    int id  = blockIdx.x * 256 + threadIdx.x;   // o*64 + k8
    int o   = id >> 6;
    int k8  = id & 63;
    const float* src = W + (size_t)o * INF + k8 * 8;
    f32x4 a = *(const f32x4*)src;
    f32x4 b = *(const f32x4*)(src + 4);
    *(short8_t*)(Wb + (size_t)k8 * (OUTF * 8) + o * 8) = pack8(a, b);
}

// acc[ni] is a 16x16 C-frag: z[m0 + lg*4 + q][w*256 + ni*16 + l15]
template <bool USE_WB>
__global__ __launch_bounds__(THREADS, 4) void fused_kernel(
    const float* __restrict__ x, const float* __restrict__ y,
    const float* __restrict__ W, const float* __restrict__ Bias,
    const unsigned short* __restrict__ Wb, float* __restrict__ out) {

    __shared__ __align__(16) char smem[SMEM_BYTES];

    const int t   = threadIdx.x;
    const int w   = t >> 6;
    const int l   = t & 63;
    const int l15 = l & 15;
    const int lg  = l >> 4;
    const int m0  = blockIdx.x * BM;

    const unsigned short* wptr = nullptr;
    const float* wf = nullptr;
    if (USE_WB) wptr = Wb + ((size_t)lg << 14) + (size_t)(w * 256 + l15) * 8; // + s*65536 + ni*128
    else        wf   = W + (size_t)(w * 256 + l15) * INF + lg * 8;            // + ni*16*INF + s*32

    // ---- stage A: 16 rows x 512 f32 -> bf16 LDS, k8-plane major,
    //      column XOR-swizzled (col = row ^ (k8&15)) for conflict-free
    //      writes AND reads ----
    #pragma unroll
    for (int i = 0; i < 2; ++i) {
        int id  = i * THREADS + t;      // 0..1023
        int row = id >> 6;              // 0..15
        int k8  = id & 63;              // 0..63
        const float* src = x + (size_t)(m0 + row) * INF + k8 * 8;
        int col = row ^ (k8 & 15);
        *(short8_t*)(smem + A_OFF + k8 * 256 + col * 16) = pack8(ld4(src), ld4(src + 4));
    }
    __syncthreads();

    f32x4_t acc[16];
    #pragma unroll
    for (int ni = 0; ni < 16; ++ni)
        acc[ni] = (f32x4_t)(0.0f);

    // ---- K loop: 16 steps of K=32; W streamed from L2; A from LDS ----
    #pragma unroll
    for (int s = 0; s < 16; ++s) {
        const int k8 = s * 4 + lg;                       // this lane-group's k8 plane
        const int col = l15 ^ (k8 & 15);                 // unswizzle
        short8_t a0 = *(const short8_t*)(smem + A_OFF + k8 * 256 + col * 16);
        #pragma unroll
        for (int ni = 0; ni < 16; ++ni) {
            short8_t bfr;
            if (USE_WB) {
                bfr = *(const short8_t*)(wptr + (size_t)s * 65536 + ni * 128);
            } else {
                const float* p = wf + (size_t)ni * 16 * INF + s * 32;
                bfr = pack8(*(const f32x4*)p, *(const f32x4*)(p + 4));
            }
            acc[ni] = __builtin_amdgcn_mfma_f32_16x16x32_bf16(a0, bfr, acc[ni], 0, 0, 0);
        }
    }

    // ---- bias (loaded after K-loop to keep K-loop register pressure low) ----
    #pragma unroll
    for (int ni = 0; ni < 16; ++ni) {
        float bv = Bias[w * 256 + ni * 16 + l15];
        #pragma unroll
        for (int q = 0; q < 4; ++q)
            acc[ni][q] += bv;
    }

    float* stats   = (float*)(smem + ST_OFF);   // [8][16][2]
    float* rowstat = (float*)(smem + RS_OFF);   // [16][2]

    // ---- per-row partial stats + 16-lane xor reduce ----
    #pragma unroll
    for (int q = 0; q < 4; ++q) {
        float s1 = 0.f, s2 = 0.f;
        #pragma unroll
        for (int ni = 0; ni < 16; ++ni) {
            float v = acc[ni][q];
            s1 += v; s2 += v * v;
        }
        #pragma unroll
        for (int d = 1; d < 16; d <<= 1) {
            s1 += __shfl_xor(s1, d);
            s2 += __shfl_xor(s2, d);
        }
        if (l15 == 0) {
            int r = lg * 4 + q;
            stats[(w * 16 + r) * 2]     = s1;
            stats[(w * 16 + r) * 2 + 1] = s2;
        }
    }
    __syncthreads();

    if (t < 16) {
        float s1 = 0.f, s2 = 0.f;
        #pragma unroll
        for (int wi = 0; wi < 8; ++wi) {
            s1 += stats[(wi * 16 + t) * 2];
            s2 += stats[(wi * 16 + t) * 2 + 1];
        }
        float mean = s1 * (1.0f / OUTF);
        float var  = s2 * (1.0f / OUTF) - mean * mean;
        rowstat[t * 2]     = mean;
        rowstat[t * 2 + 1] = rsqrtf(var + 1e-5f);
    }
    __syncthreads();

    // ---- epilogue: 4 phases of 4 rows; block LDS transpose -> full-row
    //      8KB float4 bursts on y/out (the r1 clean pattern) ----
    float* tbuf = (float*)(smem + TB_OFF);   // [4][2052]
    #pragma unroll
    for (int p = 0; p < 4; ++p) {
        if (lg == p) {                       // this lane's 4 rows are phase p
            #pragma unroll
            for (int q = 0; q < 4; ++q)
                #pragma unroll
                for (int ni = 0; ni < 16; ++ni)
                    tbuf[q * 2052 + w * 256 + ni * 16 + l15] = acc[ni][q];
        }
        __syncthreads();
        #pragma unroll
        for (int i = 0; i < 4; ++i) {
            const int r = p * 4 + i;
            f32x4 z4 = *(const f32x4*)(tbuf + i * 2052 + t * 4);
            const float mean = rowstat[r * 2];
            const float rstd = rowstat[r * 2 + 1];
            const size_t grow = (size_t)(m0 + r) * OUTF + t * 4;
            f32x4 yv = ld4(y + grow);
            f32x4 o4;
            #pragma unroll
            for (int j = 0; j < 4; ++j) {
                float zn = (z4[j] - mean) * rstd;
                o4[j] = (zn + yv[j]) * yv[j];
            }
            *(f32x4*)(out + grow) = o4;
        }
        __syncthreads();
    }
}

extern "C" void kernel_launch(void* const* d_in, const int* in_sizes, int n_in,
                              void* d_out, int out_size, void* d_ws, size_t ws_size,
                              hipStream_t stream) {
    const float* x = (const float*)d_in[0];
    const float* y = (const float*)d_in[1];
    const float* W = (const float*)d_in[2];
    const float* B = (const float*)d_in[3];
    float* out = (float*)d_out;

    if (ws_size >= (size_t)WB_BYTES) {
        unsigned short* Wb = (unsigned short*)d_ws;
        conv_w_kernel<<<512, 256, 0, stream>>>(W, Wb);
        fused_kernel<true><<<NBLK, THREADS, 0, stream>>>(x, y, W, B, Wb, out);
    } else {
        fused_kernel<false><<<NBLK, THREADS, 0, stream>>>(x, y, W, B, nullptr, out);
    }
}

// Round 9
// 220.072 us; speedup vs baseline: 6.0806x; 1.6340x over previous
//
#include <hip/hip_runtime.h>
#include <stdint.h>
#include <stddef.h>

// z = x[32768,512] @ W[2048,512]^T + B; per-row instance-norm over 2048;
// out = (z_norm + y) * y.  f32 I/O, bf16 MFMA (32x32x16) internally.
//
// Round-9: BM=32 (halves Wb L2 traffic vs r8 - the measured bottleneck),
// 1024 independent blocks, 512 threads, 1 block/CU (acc=128 AGPR).
// W streamed via global_load_lds 3-buffer chunk pipeline (32KB chunks,
// counted vmcnt(4) + raw s_barrier, never drained mid-loop) so the L2
// stream is not VGPR/latency limited. Epilogue = r1-style block LDS
// transpose (proven traffic-clean) reusing the W-buffer LDS region.

typedef float  f32x16_t __attribute__((ext_vector_type(16)));
typedef float  f32x4    __attribute__((ext_vector_type(4)));
typedef short  short8_t __attribute__((ext_vector_type(8)));

#define BATCH   32768
#define INF     512
#define OUTF    2048
#define BM      32
#define NBLK    (BATCH / BM)             // 1024
#define THREADS 512
#define WB_BYTES (OUTF * INF * 2)        // 2 MB bf16 W

// LDS layout (bytes)
#define A_OFF    0                        // 32 KB A tile: addr = k8*512 + (row^(k8&31))*16
#define WB_OFF   32768                    // 3 x 32 KB W chunk buffers
#define ST_OFF   131072                   // [8 waves][32 rows][2] f32 = 2 KB
#define RS_OFF   133120                   // [32][2] f32
#define TB_OFF   32768                    // epilogue tbuf [8][2052] f32 (reuses WB bufs)
#define SMEM_BYTES 133376

__device__ __forceinline__ unsigned short f2bf(float f) {
    unsigned int u = __builtin_bit_cast(unsigned int, f);
    u += 0x7FFFu + ((u >> 16) & 1u);     // round-to-nearest-even
    return (unsigned short)(u >> 16);
}

__device__ __forceinline__ short8_t pack8(f32x4 a, f32x4 b) {
    short8_t v;
    v[0] = (short)f2bf(a[0]); v[1] = (short)f2bf(a[1]);
    v[2] = (short)f2bf(a[2]); v[3] = (short)f2bf(a[3]);
    v[4] = (short)f2bf(b[0]); v[5] = (short)f2bf(b[1]);
    v[6] = (short)f2bf(b[2]); v[7] = (short)f2bf(b[3]);
    return v;
}

__device__ __forceinline__ f32x4 ld4(const float* p) { return *(const f32x4*)p; }

__device__ __forceinline__ void glds16(const void* g, void* l) {
    __builtin_amdgcn_global_load_lds(
        (const __attribute__((address_space(1))) unsigned int*)g,
        (__attribute__((address_space(3))) unsigned int*)l, 16, 0, 0);
}

// Prepass: W f32 [2048,512] -> Wb bf16, frag-major for 32x32x16:
// byte(s,col,half,j) = s*65536 + col*32 + half*16 + 2j  (k = s*16 + half*8 + j)
// Chunk c (=2s+ch, ch = col>=1024) is the contiguous 32 KB at c*32768.
__global__ __launch_bounds__(256) void conv_w_kernel(const float* __restrict__ W,
                                                     unsigned short* __restrict__ Wb) {
    int id  = blockIdx.x * 256 + threadIdx.x;   // col*64 + k8
    int col = id >> 6;
    int k8  = id & 63;
    const float* src = W + (size_t)col * INF + k8 * 8;
    f32x4 a = *(const f32x4*)src;
    f32x4 b = *(const f32x4*)(src + 4);
    *(short8_t*)(Wb + (size_t)(k8 >> 1) * 32768 + col * 16 + (k8 & 1) * 8) = pack8(a, b);
}

// A-frag (32x32x16): lane l -> A[row=l&31][k = s*16 + (l>>5)*8 + j]
// C-frag: col = lane&31, row = (q&3) + 8*(q>>2) + 4*(lane>>5), q=0..15
// Wave w owns cols col(n) = (n>>2)*1024 + (n&3)*256 + w*32 + c31, n=0..7.
template <bool USE_WB>
__global__ __launch_bounds__(THREADS, 2) void fused_kernel(
    const float* __restrict__ x, const float* __restrict__ y,
    const float* __restrict__ W, const float* __restrict__ Bias,
    const unsigned short* __restrict__ Wb, float* __restrict__ out) {

    __shared__ __align__(16) char smem[SMEM_BYTES];

    const int t    = threadIdx.x;
    const int w    = t >> 6;
    const int l    = t & 63;
    const int c31  = l & 31;
    const int half = l >> 5;
    const int m0   = blockIdx.x * BM;

    // ---- issue W chunks 0,1 into LDS bufs 0,1 (no VGPR cost) ----
    if constexpr (USE_WB) {
        #pragma unroll
        for (int cc = 0; cc < 2; ++cc)
            #pragma unroll
            for (int i = 0; i < 4; ++i)
                glds16((const char*)Wb + (size_t)cc * 32768 + i * 8192 + t * 16,
                       smem + WB_OFF + cc * 32768 + i * 8192 + (t >> 6) * 1024);
    }

    // ---- stage A: 32 rows x 512 f32 -> bf16 LDS, XOR-swizzled cols ----
    {
        const float* xs = x + (size_t)(m0 + w) * INF + l * 8;
        #pragma unroll
        for (int i = 0; i < 4; ++i) {   // row = i*8 + w, k8 = l
            int row = i * 8 + w;
            f32x4 a = ld4(xs + i * 8 * INF);
            f32x4 b = ld4(xs + i * 8 * INF + 4);
            *(short8_t*)(smem + A_OFF + l * 512 + ((row ^ (l & 31)) * 16)) = pack8(a, b);
        }
    }
    if constexpr (USE_WB) {
        __asm__ volatile("s_waitcnt lgkmcnt(0)" ::: "memory");  // A writes done; keep glds queue
        __builtin_amdgcn_s_barrier();
    } else {
        __syncthreads();
    }

    f32x16_t acc[8];
    #pragma unroll
    for (int n = 0; n < 8; ++n)
        acc[n] = (f32x16_t)(0.0f);

    // ---- K loop: 64 chunks (s = c>>1, col-half = c&1), 3-buffer pipeline ----
    short8_t afrag;
    #pragma unroll
    for (int c = 0; c < 64; ++c) {
        const int s  = c >> 1;
        const int ch = c & 1;
        if constexpr (USE_WB) {
            if (c == 63) { __asm__ volatile("s_waitcnt vmcnt(0)" ::: "memory"); }
            else         { __asm__ volatile("s_waitcnt vmcnt(4)" ::: "memory"); }
            __builtin_amdgcn_s_barrier();   // chunk c visible to all; buf (c+2)%3 free
            if (c + 2 < 64) {
                #pragma unroll
                for (int i = 0; i < 4; ++i)
                    glds16((const char*)Wb + (size_t)(c + 2) * 32768 + i * 8192 + t * 16,
                           smem + WB_OFF + ((c + 2) % 3) * 32768 + i * 8192 + (t >> 6) * 1024);
            }
        }
        if (ch == 0) {
            const int k8 = 2 * s + half;
            afrag = *(const short8_t*)(smem + A_OFF + k8 * 512 + ((c31 ^ (k8 & 31)) * 16));
        }
        #pragma unroll
        for (int n4 = 0; n4 < 4; ++n4) {
            const int n = ch * 4 + n4;
            short8_t bfr;
            if constexpr (USE_WB) {
                const int colh = n4 * 256 + w * 32 + c31;     // col within this 1024-half
                bfr = *(const short8_t*)(smem + WB_OFF + (c % 3) * 32768 + colh * 32 + half * 16);
            } else {
                const int col = ch * 1024 + n4 * 256 + w * 32 + c31;
                const float* p = W + (size_t)col * INF + s * 16 + half * 8;
                bfr = pack8(*(const f32x4*)p, *(const f32x4*)(p + 4));
            }
            acc[n] = __builtin_amdgcn_mfma_f32_32x32x16_bf16(afrag, bfr, acc[n], 0, 0, 0);
        }
    }

    // ---- bias ----
    #pragma unroll
    for (int n = 0; n < 8; ++n) {
        float bv = Bias[(n >> 2) * 1024 + (n & 3) * 256 + w * 32 + c31];
        #pragma unroll
        for (int q = 0; q < 16; ++q)
            acc[n][q] += bv;
    }

    float* stats   = (float*)(smem + ST_OFF);   // [8][32][2]
    float* rowstat = (float*)(smem + RS_OFF);   // [32][2]

    // ---- per-row stats: lane partial over 8 frags, 32-lane xor reduce ----
    #pragma unroll
    for (int q = 0; q < 16; ++q) {
        float s1 = 0.f, s2 = 0.f;
        #pragma unroll
        for (int n = 0; n < 8; ++n) {
            float v = acc[n][q];
            s1 += v; s2 += v * v;
        }
        #pragma unroll
        for (int d = 1; d < 32; d <<= 1) {
            s1 += __shfl_xor(s1, d);
            s2 += __shfl_xor(s2, d);
        }
        if (c31 == 0) {
            int r = 4 * half + (q & 3) + 8 * (q >> 2);
            stats[(w * 32 + r) * 2]     = s1;
            stats[(w * 32 + r) * 2 + 1] = s2;
        }
    }
    __syncthreads();

    if (t < 32) {
        float s1 = 0.f, s2 = 0.f;
        #pragma unroll
        for (int wi = 0; wi < 8; ++wi) {
            s1 += stats[(wi * 32 + t) * 2];
            s2 += stats[(wi * 32 + t) * 2 + 1];
        }
        float mean = s1 * (1.0f / OUTF);
        float var  = s2 * (1.0f / OUTF) - mean * mean;
        rowstat[t * 2]     = mean;
        rowstat[t * 2 + 1] = rsqrtf(var + 1e-5f);
    }
    __syncthreads();

    // ---- epilogue: 4 phases of 8 rows; block LDS transpose (tbuf reuses
    //      the W-chunk buffers) -> full-row 8KB float4 bursts on y/out ----
    float* tbuf = (float*)(smem + TB_OFF);   // [8][2052]
    #pragma unroll
    for (int p = 0; p < 4; ++p) {
        #pragma unroll
        for (int qq = 0; qq < 4; ++qq) {
            const int q  = 4 * p + qq;
            const int rl = qq + 4 * half;          // row within phase
            #pragma unroll
            for (int n = 0; n < 8; ++n) {
                const int col = (n >> 2) * 1024 + (n & 3) * 256 + w * 32 + c31;
                tbuf[rl * 2052 + col] = acc[n][q];
            }
        }
        __syncthreads();
        #pragma unroll
        for (int i = 0; i < 8; ++i) {
            const int r = p * 8 + i;
            f32x4 z4 = *(const f32x4*)(tbuf + i * 2052 + t * 4);
            const float mean = rowstat[r * 2];
            const float rstd = rowstat[r * 2 + 1];
            const size_t grow = (size_t)(m0 + r) * OUTF + t * 4;
            f32x4 yv = ld4(y + grow);
            f32x4 o4;
            #pragma unroll
            for (int j = 0; j < 4; ++j) {
                float zn = (z4[j] - mean) * rstd;
                o4[j] = (zn + yv[j]) * yv[j];
            }
            *(f32x4*)(out + grow) = o4;
        }
        __syncthreads();
    }
}

extern "C" void kernel_launch(void* const* d_in, const int* in_sizes, int n_in,
                              void* d_out, int out_size, void* d_ws, size_t ws_size,
                              hipStream_t stream) {
    const float* x = (const float*)d_in[0];
    const float* y = (const float*)d_in[1];
    const float* W = (const float*)d_in[2];
    const float* B = (const float*)d_in[3];
    float* out = (float*)d_out;

    if (ws_size >= (size_t)WB_BYTES) {
        unsigned short* Wb = (unsigned short*)d_ws;
        conv_w_kernel<<<512, 256, 0, stream>>>(W, Wb);
        fused_kernel<true><<<NBLK, THREADS, 0, stream>>>(x, y, W, B, Wb, out);
    } else {
        fused_kernel<false><<<NBLK, THREADS, 0, stream>>>(x, y, W, B, nullptr, out);
    }
}

// Round 10
// 219.559 us; speedup vs baseline: 6.0948x; 1.0023x over previous
//
#include <hip/hip_runtime.h>
#include <stdint.h>
#include <stddef.h>

// z = x[32768,512] @ W[2048,512]^T + B; per-row instance-norm over 2048;
// out = (z_norm + y) * y.  f32 I/O, bf16 MFMA (32x32x16) internally.
//
// Round-10 = round-9 with ONE change: W chunk interior layout
// [colh][half][16B] -> [half][colh][16B], making each lane's B-frag read
// contiguous (16B stride across lanes) => conflict-free ds_read_b128.
// r9 measured 8.4M SQ_LDS_BANK_CONFLICT cycles from the 32B-stride reads.

typedef float  f32x16_t __attribute__((ext_vector_type(16)));
typedef float  f32x4    __attribute__((ext_vector_type(4)));
typedef short  short8_t __attribute__((ext_vector_type(8)));

#define BATCH   32768
#define INF     512
#define OUTF    2048
#define BM      32
#define NBLK    (BATCH / BM)             // 1024
#define THREADS 512
#define WB_BYTES (OUTF * INF * 2)        // 2 MB bf16 W

// LDS layout (bytes)
#define A_OFF    0                        // 32 KB A tile: addr = k8*512 + (row^(k8&31))*16
#define WB_OFF   32768                    // 3 x 32 KB W chunk buffers
#define ST_OFF   131072                   // [8 waves][32 rows][2] f32 = 2 KB
#define RS_OFF   133120                   // [32][2] f32
#define TB_OFF   32768                    // epilogue tbuf [8][2052] f32 (reuses WB bufs)
#define SMEM_BYTES 133376

__device__ __forceinline__ unsigned short f2bf(float f) {
    unsigned int u = __builtin_bit_cast(unsigned int, f);
    u += 0x7FFFu + ((u >> 16) & 1u);     // round-to-nearest-even
    return (unsigned short)(u >> 16);
}

__device__ __forceinline__ short8_t pack8(f32x4 a, f32x4 b) {
    short8_t v;
    v[0] = (short)f2bf(a[0]); v[1] = (short)f2bf(a[1]);
    v[2] = (short)f2bf(a[2]); v[3] = (short)f2bf(a[3]);
    v[4] = (short)f2bf(b[0]); v[5] = (short)f2bf(b[1]);
    v[6] = (short)f2bf(b[2]); v[7] = (short)f2bf(b[3]);
    return v;
}

__device__ __forceinline__ f32x4 ld4(const float* p) { return *(const f32x4*)p; }

__device__ __forceinline__ void glds16(const void* g, void* l) {
    __builtin_amdgcn_global_load_lds(
        (const __attribute__((address_space(1))) unsigned int*)g,
        (__attribute__((address_space(3))) unsigned int*)l, 16, 0, 0);
}

// Prepass: W f32 [2048,512] -> Wb bf16, chunk-major for 32x32x16:
// chunk c = 2s + ch (ch = col>=1024) is 32 KB at c*32768 bytes.
// Interior: elem = half*8192 + colh*8 + j  (k = s*16 + half*8 + j, colh = col&1023)
__global__ __launch_bounds__(256) void conv_w_kernel(const float* __restrict__ W,
                                                     unsigned short* __restrict__ Wb) {
    int id  = blockIdx.x * 256 + threadIdx.x;   // col*64 + k8
    int col = id >> 6;
    int k8  = id & 63;
    const float* src = W + (size_t)col * INF + k8 * 8;
    f32x4 a = *(const f32x4*)src;
    f32x4 b = *(const f32x4*)(src + 4);
    const int c = (k8 & 62) + (col >> 10);      // 2*(k8>>1) + ch
    *(short8_t*)(Wb + (size_t)c * 16384 + (k8 & 1) * 8192 + (col & 1023) * 8) = pack8(a, b);
}

// A-frag (32x32x16): lane l -> A[row=l&31][k = s*16 + (l>>5)*8 + j]
// C-frag: col = lane&31, row = (q&3) + 8*(q>>2) + 4*(lane>>5), q=0..15
// Wave w owns cols col(n) = (n>>2)*1024 + (n&3)*256 + w*32 + c31, n=0..7.
template <bool USE_WB>
__global__ __launch_bounds__(THREADS, 2) void fused_kernel(
    const float* __restrict__ x, const float* __restrict__ y,
    const float* __restrict__ W, const float* __restrict__ Bias,
    const unsigned short* __restrict__ Wb, float* __restrict__ out) {

    __shared__ __align__(16) char smem[SMEM_BYTES];

    const int t    = threadIdx.x;
    const int w    = t >> 6;
    const int l    = t & 63;
    const int c31  = l & 31;
    const int half = l >> 5;
    const int m0   = blockIdx.x * BM;

    // ---- issue W chunks 0,1 into LDS bufs 0,1 (no VGPR cost) ----
    if constexpr (USE_WB) {
        #pragma unroll
        for (int cc = 0; cc < 2; ++cc)
            #pragma unroll
            for (int i = 0; i < 4; ++i)
                glds16((const char*)Wb + (size_t)cc * 32768 + i * 8192 + t * 16,
                       smem + WB_OFF + cc * 32768 + i * 8192 + (t >> 6) * 1024);
    }

    // ---- stage A: 32 rows x 512 f32 -> bf16 LDS, XOR-swizzled cols ----
    {
        const float* xs = x + (size_t)(m0 + w) * INF + l * 8;
        #pragma unroll
        for (int i = 0; i < 4; ++i) {   // row = i*8 + w, k8 = l
            int row = i * 8 + w;
            f32x4 a = ld4(xs + i * 8 * INF);
            f32x4 b = ld4(xs + i * 8 * INF + 4);
            *(short8_t*)(smem + A_OFF + l * 512 + ((row ^ (l & 31)) * 16)) = pack8(a, b);
        }
    }
    if constexpr (USE_WB) {
        __asm__ volatile("s_waitcnt lgkmcnt(0)" ::: "memory");  // A writes done; keep glds queue
        __builtin_amdgcn_s_barrier();
    } else {
        __syncthreads();
    }

    f32x16_t acc[8];
    #pragma unroll
    for (int n = 0; n < 8; ++n)
        acc[n] = (f32x16_t)(0.0f);

    // ---- K loop: 64 chunks (s = c>>1, col-half = c&1), 3-buffer pipeline ----
    short8_t afrag;
    #pragma unroll
    for (int c = 0; c < 64; ++c) {
        const int s  = c >> 1;
        const int ch = c & 1;
        if constexpr (USE_WB) {
            if (c == 63) { __asm__ volatile("s_waitcnt vmcnt(0)" ::: "memory"); }
            else         { __asm__ volatile("s_waitcnt vmcnt(4)" ::: "memory"); }
            __builtin_amdgcn_s_barrier();   // chunk c visible to all; buf (c+2)%3 free
            if (c + 2 < 64) {
                #pragma unroll
                for (int i = 0; i < 4; ++i)
                    glds16((const char*)Wb + (size_t)(c + 2) * 32768 + i * 8192 + t * 16,
                           smem + WB_OFF + ((c + 2) % 3) * 32768 + i * 8192 + (t >> 6) * 1024);
            }
        }
        if (ch == 0) {
            const int k8 = 2 * s + half;
            afrag = *(const short8_t*)(smem + A_OFF + k8 * 512 + ((c31 ^ (k8 & 31)) * 16));
        }
        #pragma unroll
        for (int n4 = 0; n4 < 4; ++n4) {
            const int n = ch * 4 + n4;
            short8_t bfr;
            if constexpr (USE_WB) {
                const int colh = n4 * 256 + w * 32 + c31;     // col within this 1024-half
                bfr = *(const short8_t*)(smem + WB_OFF + (c % 3) * 32768 + half * 16384 + colh * 16);
            } else {
                const int col = ch * 1024 + n4 * 256 + w * 32 + c31;
                const float* p = W + (size_t)col * INF + s * 16 + half * 8;
                bfr = pack8(*(const f32x4*)p, *(const f32x4*)(p + 4));
            }
            acc[n] = __builtin_amdgcn_mfma_f32_32x32x16_bf16(afrag, bfr, acc[n], 0, 0, 0);
        }
    }

    // ---- bias ----
    #pragma unroll
    for (int n = 0; n < 8; ++n) {
        float bv = Bias[(n >> 2) * 1024 + (n & 3) * 256 + w * 32 + c31];
        #pragma unroll
        for (int q = 0; q < 16; ++q)
            acc[n][q] += bv;
    }

    float* stats   = (float*)(smem + ST_OFF);   // [8][32][2]
    float* rowstat = (float*)(smem + RS_OFF);   // [32][2]

    // ---- per-row stats: lane partial over 8 frags, 32-lane xor reduce ----
    #pragma unroll
    for (int q = 0; q < 16; ++q) {
        float s1 = 0.f, s2 = 0.f;
        #pragma unroll
        for (int n = 0; n < 8; ++n) {
            float v = acc[n][q];
            s1 += v; s2 += v * v;
        }
        #pragma unroll
        for (int d = 1; d < 32; d <<= 1) {
            s1 += __shfl_xor(s1, d);
            s2 += __shfl_xor(s2, d);
        }
        if (c31 == 0) {
            int r = 4 * half + (q & 3) + 8 * (q >> 2);
            stats[(w * 32 + r) * 2]     = s1;
            stats[(w * 32 + r) * 2 + 1] = s2;
        }
    }
    __syncthreads();

    if (t < 32) {
        float s1 = 0.f, s2 = 0.f;
        #pragma unroll
        for (int wi = 0; wi < 8; ++wi) {
            s1 += stats[(wi * 32 + t) * 2];
            s2 += stats[(wi * 32 + t) * 2 + 1];
        }
        float mean = s1 * (1.0f / OUTF);
        float var  = s2 * (1.0f / OUTF) - mean * mean;
        rowstat[t * 2]     = mean;
        rowstat[t * 2 + 1] = rsqrtf(var + 1e-5f);
    }
    __syncthreads();

    // ---- epilogue: 4 phases of 8 rows; block LDS transpose (tbuf reuses
    //      the W-chunk buffers) -> full-row 8KB float4 bursts on y/out ----
    float* tbuf = (float*)(smem + TB_OFF);   // [8][2052]
    #pragma unroll
    for (int p = 0; p < 4; ++p) {
        #pragma unroll
        for (int qq = 0; qq < 4; ++qq) {
            const int q  = 4 * p + qq;
            const int rl = qq + 4 * half;          // row within phase
            #pragma unroll
            for (int n = 0; n < 8; ++n) {
                const int col = (n >> 2) * 1024 + (n & 3) * 256 + w * 32 + c31;
                tbuf[rl * 2052 + col] = acc[n][q];
            }
        }
        __syncthreads();
        #pragma unroll
        for (int i = 0; i < 8; ++i) {
            const int r = p * 8 + i;
            f32x4 z4 = *(const f32x4*)(tbuf + i * 2052 + t * 4);
            const float mean = rowstat[r * 2];
            const float rstd = rowstat[r * 2 + 1];
            const size_t grow = (size_t)(m0 + r) * OUTF + t * 4;
            f32x4 yv = ld4(y + grow);
            f32x4 o4;
            #pragma unroll
            for (int j = 0; j < 4; ++j) {
                float zn = (z4[j] - mean) * rstd;
                o4[j] = (zn + yv[j]) * yv[j];
            }
            *(f32x4*)(out + grow) = o4;
        }
        __syncthreads();
    }
}

extern "C" void kernel_launch(void* const* d_in, const int* in_sizes, int n_in,
                              void* d_out, int out_size, void* d_ws, size_t ws_size,
                              hipStream_t stream) {
    const float* x = (const float*)d_in[0];
    const float* y = (const float*)d_in[1];
    const float* W = (const float*)d_in[2];
    const float* B = (const float*)d_in[3];
    float* out = (float*)d_out;

    if (ws_size >= (size_t)WB_BYTES) {
        unsigned short* Wb = (unsigned short*)d_ws;
        conv_w_kernel<<<512, 256, 0, stream>>>(W, Wb);
        fused_kernel<true><<<NBLK, THREADS, 0, stream>>>(x, y, W, B, Wb, out);
    } else {
        fused_kernel<false><<<NBLK, THREADS, 0, stream>>>(x, y, W, B, nullptr, out);
    }
}

// Round 12
// 195.767 us; speedup vs baseline: 6.8355x; 1.1215x over previous
//
#include <hip/hip_runtime.h>
#include <stdint.h>
#include <stddef.h>

// z = x[32768,512] @ W[2048,512]^T + B; per-row instance-norm over 2048;
// out = (z_norm + y) * y.  f32 I/O; GEMM in INT8 MFMA (32x32x16_i8) with
// per-row x-scales and per-col W-scales, dequantized in the epilogue.
//
// Round-12 = round-11 with the SW_OFF compile fix.
// Rationale: rounds 8/10 showed an ~8-10 TB/s effective aggregate ceiling on
// the W stream (L2->CU); W bytes/block are irreducible at BM=32, so halve
// them via dtype: int8. Halves L2 stream, glds writes, B ds_reads, chunk
// count (64->32 barriers), MFMA count. Structure otherwise = round 10
// (glds 3-buffer pipeline, counted vmcnt, r1-style clean epilogue).

typedef float  f32x4  __attribute__((ext_vector_type(4)));
typedef int    i32x16 __attribute__((ext_vector_type(16)));

#define BATCH   32768
#define INF     512
#define OUTF    2048
#define BM      32
#define NBLK    (BATCH / BM)             // 1024
#define THREADS 512
#define WQ_BYTES (OUTF * INF)            // 1 MB int8 W
#define SW_OFF   WQ_BYTES                // sw[2048] f32 after Wq
#define WS_NEED  (WQ_BYTES + OUTF * 4)

// LDS layout (bytes)
#define A_OFF    0                        // [k8(64)][row^swz(32)][8B], stride 264
#define WQ_LDS   17408                    // 3 x 32 KB W chunk buffers
#define ST_OFF   115712                   // [8 waves][32 rows][2] f32
#define RS_OFF   117760                   // [32][2] f32 (mean, rstd)
#define RSC_OFF  118016                   // rowscale[32] f32
#define TB_OFF   WQ_LDS                   // epilogue tbuf [8][2052] f32 (reuse)
#define SMEM_BYTES 118144

__device__ __forceinline__ f32x4 ld4(const float* p) { return *(const f32x4*)p; }

__device__ __forceinline__ void glds16(const void* g, void* l) {
    __builtin_amdgcn_global_load_lds(
        (const __attribute__((address_space(1))) unsigned int*)g,
        (__attribute__((address_space(3))) unsigned int*)l, 16, 0, 0);
}

__device__ __forceinline__ long long quant8(f32x4 a, f32x4 b, float inv) {
    unsigned int lo = 0, hi = 0;
    int q;
    q = (int)__builtin_rintf(a[0] * inv); lo |= (unsigned)(q & 255);
    q = (int)__builtin_rintf(a[1] * inv); lo |= (unsigned)(q & 255) << 8;
    q = (int)__builtin_rintf(a[2] * inv); lo |= (unsigned)(q & 255) << 16;
    q = (int)__builtin_rintf(a[3] * inv); lo |= (unsigned)(q & 255) << 24;
    q = (int)__builtin_rintf(b[0] * inv); hi |= (unsigned)(q & 255);
    q = (int)__builtin_rintf(b[1] * inv); hi |= (unsigned)(q & 255) << 8;
    q = (int)__builtin_rintf(b[2] * inv); hi |= (unsigned)(q & 255) << 16;
    q = (int)__builtin_rintf(b[3] * inv); hi |= (unsigned)(q & 255) << 24;
    return (long long)(((unsigned long long)hi << 32) | lo);
}

// Prepass: W f32 [2048,512] -> Wq int8 chunk-major + sw[2048] f32 scales.
// chunk c = s-step (K=16) = 32 KB: off = c*32768 + half*16384 + w*2048
//         + n*256 + c31*8  (col = n*256 + w*32 + c31; k = c*16 + half*8 + j)
__global__ __launch_bounds__(64) void conv_w_kernel(const float* __restrict__ W,
                                                    char* __restrict__ Wq,
                                                    float* __restrict__ sw) {
    const int o = blockIdx.x;        // col
    const int l = threadIdx.x;       // k8 = l
    const float* src = W + (size_t)o * INF + l * 8;
    f32x4 a = ld4(src), b = ld4(src + 4);
    float m = 0.f;
    #pragma unroll
    for (int j = 0; j < 4; ++j) m = fmaxf(m, fmaxf(fabsf(a[j]), fabsf(b[j])));
    #pragma unroll
    for (int d = 1; d < 64; d <<= 1) m = fmaxf(m, __shfl_xor(m, d));
    const float inv = m > 0.f ? 127.0f / m : 0.f;
    long long v = quant8(a, b, inv);
    const int s = l >> 1, half = l & 1;
    size_t off = (size_t)s * 32768 + half * 16384 +
                 ((o >> 5) & 7) * 2048 + (o >> 8) * 256 + (o & 31) * 8;
    *(long long*)(Wq + off) = v;
    if (l == 0) sw[o] = m > 0.f ? m * (1.0f / 127.0f) : 0.f;
}

// A-frag (32x32x16_i8): lane l -> A[row=l&31][k = c*16 + (l>>5)*8 + j]
// C-frag: col = lane&31, row = (q&3) + 8*(q>>2) + 4*(lane>>5), q=0..15
// Wave w owns cols col(n) = n*256 + w*32 + c31, n = 0..7.
__global__ __launch_bounds__(THREADS, 2) void fused_kernel(
    const float* __restrict__ x, const float* __restrict__ y,
    const float* __restrict__ Bias, const char* __restrict__ Wq,
    const float* __restrict__ sw, float* __restrict__ out) {

    __shared__ __align__(16) char smem[SMEM_BYTES];

    const int t    = threadIdx.x;
    const int w    = t >> 6;
    const int l    = t & 63;
    const int c31  = l & 31;
    const int half = l >> 5;
    const int m0   = blockIdx.x * BM;

    // ---- issue W chunks 0,1 into LDS bufs 0,1 ----
    #pragma unroll
    for (int cc = 0; cc < 2; ++cc)
        #pragma unroll
        for (int i = 0; i < 4; ++i)
            glds16(Wq + (size_t)cc * 32768 + i * 8192 + t * 16,
                   smem + WQ_LDS + cc * 32768 + i * 8192 + w * 1024);

    // ---- stage A: quantize x rows to int8 in LDS; rowscale[32] ----
    float* rowscale = (float*)(smem + RSC_OFF);
    {
        const float* xs = x + (size_t)(m0 + w) * INF + l * 8;
        #pragma unroll
        for (int i = 0; i < 4; ++i) {      // row = w + 8i; lane l = k8 plane
            const int row = w + 8 * i;
            f32x4 a = ld4(xs + i * 8 * INF), b = ld4(xs + i * 8 * INF + 4);
            float m = 0.f;
            #pragma unroll
            for (int j = 0; j < 4; ++j) m = fmaxf(m, fmaxf(fabsf(a[j]), fabsf(b[j])));
            #pragma unroll
            for (int d = 1; d < 64; d <<= 1) m = fmaxf(m, __shfl_xor(m, d));
            const float inv = m > 0.f ? 127.0f / m : 0.f;
            *(long long*)(smem + A_OFF + l * 264 + ((row ^ (l & 31)) & 31) * 8) =
                quant8(a, b, inv);
            if (l == 0) rowscale[row] = m > 0.f ? m * (1.0f / 127.0f) : 0.f;
        }
    }
    __asm__ volatile("s_waitcnt lgkmcnt(0)" ::: "memory");  // A+rowscale visible
    __builtin_amdgcn_s_barrier();

    i32x16 acc[8];
    #pragma unroll
    for (int n = 0; n < 8; ++n) acc[n] = (i32x16)(0);

    // ---- K loop: 32 chunks (one K=16 step each), 3-buffer glds pipeline ----
    #pragma unroll
    for (int c = 0; c < 32; ++c) {
        if (c == 31) { __asm__ volatile("s_waitcnt vmcnt(0)" ::: "memory"); }
        else         { __asm__ volatile("s_waitcnt vmcnt(4)" ::: "memory"); }
        __builtin_amdgcn_s_barrier();   // chunk c ready; buf (c+2)%3 free
        if (c + 2 < 32) {
            #pragma unroll
            for (int i = 0; i < 4; ++i)
                glds16(Wq + (size_t)(c + 2) * 32768 + i * 8192 + t * 16,
                       smem + WQ_LDS + ((c + 2) % 3) * 32768 + i * 8192 + w * 1024);
        }
        const int k8 = c * 2 + half;
        long long af = *(const long long*)(smem + A_OFF + k8 * 264 +
                                           ((c31 ^ (k8 & 31)) & 31) * 8);
        const char* bb = smem + WQ_LDS + (c % 3) * 32768 + half * 16384 +
                         w * 2048 + c31 * 8;
        #pragma unroll
        for (int n = 0; n < 8; ++n) {
            long long bf = *(const long long*)(bb + n * 256);
            acc[n] = __builtin_amdgcn_mfma_i32_32x32x16_i8(af, bf, acc[n], 0, 0, 0);
        }
    }

    // ---- dequant scales ----
    float swv[8], bsv[8];
    #pragma unroll
    for (int n = 0; n < 8; ++n) {
        const int col = n * 256 + w * 32 + c31;
        swv[n] = sw[col];
        bsv[n] = Bias[col];
    }
    float sxv[16];
    #pragma unroll
    for (int q = 0; q < 16; ++q)
        sxv[q] = rowscale[4 * half + (q & 3) + 8 * (q >> 2)];

    float* stats   = (float*)(smem + ST_OFF);   // [8][32][2]
    float* rowstat = (float*)(smem + RS_OFF);   // [32][2]

    // ---- per-row stats (z recomputed from acc on the fly) ----
    #pragma unroll
    for (int q = 0; q < 16; ++q) {
        float s1 = 0.f, s2 = 0.f;
        #pragma unroll
        for (int n = 0; n < 8; ++n) {
            float z = fmaf((float)acc[n][q], sxv[q] * swv[n], bsv[n]);
            s1 += z; s2 += z * z;
        }
        #pragma unroll
        for (int d = 1; d < 32; d <<= 1) {
            s1 += __shfl_xor(s1, d);
            s2 += __shfl_xor(s2, d);
        }
        if (c31 == 0) {
            const int r = 4 * half + (q & 3) + 8 * (q >> 2);
            stats[(w * 32 + r) * 2]     = s1;
            stats[(w * 32 + r) * 2 + 1] = s2;
        }
    }
    __syncthreads();

    if (t < 32) {
        float s1 = 0.f, s2 = 0.f;
        #pragma unroll
        for (int wi = 0; wi < 8; ++wi) {
            s1 += stats[(wi * 32 + t) * 2];
            s2 += stats[(wi * 32 + t) * 2 + 1];
        }
        const float mean = s1 * (1.0f / OUTF);
        const float var  = s2 * (1.0f / OUTF) - mean * mean;
        rowstat[t * 2]     = mean;
        rowstat[t * 2 + 1] = rsqrtf(var + 1e-5f);
    }
    __syncthreads();

    // ---- epilogue: 4 phases of 8 rows; block LDS transpose (tbuf reuses
    //      W buffers) -> full-row 8KB float4 bursts on y/out ----
    float* tbuf = (float*)(smem + TB_OFF);   // [8][2052]
    #pragma unroll
    for (int p = 0; p < 4; ++p) {
        #pragma unroll
        for (int qq = 0; qq < 4; ++qq) {
            const int q  = 4 * p + qq;
            const int rl = qq + 4 * half;
            #pragma unroll
            for (int n = 0; n < 8; ++n) {
                const int col = n * 256 + w * 32 + c31;
                tbuf[rl * 2052 + col] = fmaf((float)acc[n][q], sxv[q] * swv[n], bsv[n]);
            }
        }
        __syncthreads();
        #pragma unroll
        for (int i = 0; i < 8; ++i) {
            const int r = p * 8 + i;
            f32x4 z4 = *(const f32x4*)(tbuf + i * 2052 + t * 4);
            const float mean = rowstat[r * 2];
            const float rstd = rowstat[r * 2 + 1];
            const size_t grow = (size_t)(m0 + r) * OUTF + t * 4;
            f32x4 yv = ld4(y + grow);
            f32x4 o4;
            #pragma unroll
            for (int j = 0; j < 4; ++j) {
                float zn = (z4[j] - mean) * rstd;
                o4[j] = (zn + yv[j]) * yv[j];
            }
            *(f32x4*)(out + grow) = o4;
        }
        __syncthreads();
    }
}

// Correctness-only fallback if workspace is too small (never expected).
__global__ __launch_bounds__(256) void naive_kernel(
    const float* __restrict__ x, const float* __restrict__ y,
    const float* __restrict__ W, const float* __restrict__ Bias,
    float* __restrict__ out) {
    const int row = blockIdx.x, t = threadIdx.x;
    __shared__ float xs[INF];
    __shared__ float zs[OUTF];
    __shared__ float red1[4], red2[4];
    for (int i = t; i < INF; i += 256) xs[i] = x[(size_t)row * INF + i];
    __syncthreads();
    for (int c = t; c < OUTF; c += 256) {
        const float* wr = W + (size_t)c * INF;
        float s = 0.f;
        for (int k = 0; k < INF; ++k) s += xs[k] * wr[k];
        zs[c] = s + Bias[c];
    }
    __syncthreads();
    float s1 = 0.f, s2 = 0.f;
    for (int c = t; c < OUTF; c += 256) { float v = zs[c]; s1 += v; s2 += v * v; }
    for (int d = 1; d < 64; d <<= 1) { s1 += __shfl_xor(s1, d); s2 += __shfl_xor(s2, d); }
    if ((t & 63) == 0) { red1[t >> 6] = s1; red2[t >> 6] = s2; }
    __syncthreads();
    float ts1 = red1[0] + red1[1] + red1[2] + red1[3];
    float ts2 = red2[0] + red2[1] + red2[2] + red2[3];
    const float mean = ts1 * (1.0f / OUTF);
    const float rstd = rsqrtf(ts2 * (1.0f / OUTF) - mean * mean + 1e-5f);
    for (int c = t; c < OUTF; c += 256) {
        const size_t off = (size_t)row * OUTF + c;
        float yv = y[off];
        float zn = (zs[c] - mean) * rstd;
        out[off] = (zn + yv) * yv;
    }
}

extern "C" void kernel_launch(void* const* d_in, const int* in_sizes, int n_in,
                              void* d_out, int out_size, void* d_ws, size_t ws_size,
                              hipStream_t stream) {
    const float* x = (const float*)d_in[0];
    const float* y = (const float*)d_in[1];
    const float* W = (const float*)d_in[2];
    const float* B = (const float*)d_in[3];
    float* out = (float*)d_out;

    if (ws_size >= (size_t)WS_NEED) {
        char*  Wq = (char*)d_ws;
        float* sw = (float*)((char*)d_ws + SW_OFF);
        conv_w_kernel<<<OUTF, 64, 0, stream>>>(W, Wq, sw);
        fused_kernel<<<NBLK, THREADS, 0, stream>>>(x, y, B, Wq, sw, out);
    } else {
        naive_kernel<<<BATCH, 256, 0, stream>>>(x, y, W, B, out);
    }
}